// Round 1
// baseline (344.480 us; speedup 1.0000x reference)
//
#include <hip/hip_runtime.h>

// Tensor-product nonlinearity, B=512, MUL=64, l in {0,1,2}.
// out0: (512, 3*4096, 1), out1: (512, 4*4096, 3), out2: (512, 4*4096, 5)
// flat-concatenated in d_out in that order.

#define OUT1_BASE (512 * 12288)               // 6291456
#define OUT2_BASE (OUT1_BASE + 512 * 49152)   // 31457280

// s_w layout offsets (order = input order)
#define WO_000 0
#define WO_011 1
#define WO_022 10
#define WO_110 35
#define WO_111 44
#define WO_112 71
#define WO_121 116
#define WO_122 161
#define WO_220 236
#define WO_221 261
#define WO_222 336
#define W_TOTAL 461

__global__ __launch_bounds__(256) void tp_kernel(
    const float* __restrict__ x0, const float* __restrict__ x1, const float* __restrict__ x2,
    const float* __restrict__ w000, const float* __restrict__ w011, const float* __restrict__ w022,
    const float* __restrict__ w110, const float* __restrict__ w111, const float* __restrict__ w112,
    const float* __restrict__ w121, const float* __restrict__ w122,
    const float* __restrict__ w220, const float* __restrict__ w221, const float* __restrict__ w222,
    float* __restrict__ out)
{
    __shared__ float s_x0[64];
    __shared__ float s_x1[192];
    __shared__ float s_x2[320];
    __shared__ float s_w[W_TOTAL];

    const int b    = blockIdx.x >> 4;   // 0..511
    const int tile = blockIdx.x & 15;   // 0..15
    const int t    = threadIdx.x;       // 0..255

    // ---- cooperative staging ----
    if (t < 64)  s_x0[t] = x0[b * 64 + t];
    if (t < 192) s_x1[t] = x1[b * 192 + t];
#pragma unroll
    for (int idx = t; idx < 320; idx += 256) s_x2[idx] = x2[b * 320 + idx];

    if (t < 1)   s_w[WO_000 + t] = w000[t];
    if (t < 9)   s_w[WO_011 + t] = w011[t];
    if (t < 25)  s_w[WO_022 + t] = w022[t];
    if (t < 9)   s_w[WO_110 + t] = w110[t];
    if (t < 27)  s_w[WO_111 + t] = w111[t];
    if (t < 45)  s_w[WO_112 + t] = w112[t];
    if (t < 45)  s_w[WO_121 + t] = w121[t];
    if (t < 75)  s_w[WO_122 + t] = w122[t];
    if (t < 25)  s_w[WO_220 + t] = w220[t];
    if (t < 75)  s_w[WO_221 + t] = w221[t];
    if (t < 125) s_w[WO_222 + t] = w222[t];

    __syncthreads();

    const int c = tile * 256 + t;  // 0..4095 = i*64 + j
    const int i = c >> 6;          // wave-uniform
    const int j = c & 63;          // lane id

    // ---- load per-thread x fragments from LDS ----
    const float a0 = s_x0[i];
    const float b0 = s_x0[j];
    float a1m[3], b1n[3], a2m[5], b2n[5];
#pragma unroll
    for (int m = 0; m < 3; ++m) a1m[m] = s_x1[i * 3 + m];
#pragma unroll
    for (int n = 0; n < 3; ++n) b1n[n] = s_x1[j * 3 + n];
#pragma unroll
    for (int m = 0; m < 5; ++m) a2m[m] = s_x2[i * 5 + m];
#pragma unroll
    for (int n = 0; n < 5; ++n) b2n[n] = s_x2[j * 5 + n];

    float* __restrict__ out0 = out + (size_t)b * 12288;
    float* __restrict__ out1 = out + OUT1_BASE + (size_t)b * 49152;
    float* __restrict__ out2 = out + OUT2_BASE + (size_t)b * 81920;

    // ---------------- pair (0,0): (0,0,0) -> out0 block 0 ----------------
    out0[c] = s_w[WO_000] * (a0 * b0);

    // ---------------- pair (0,1): (0,1,1) -> out1 block 0 ----------------
    {
        float o[3] = {0.f, 0.f, 0.f};
#pragma unroll
        for (int n = 0; n < 3; ++n) {
            const float p = a0 * b1n[n];
#pragma unroll
            for (int M = 0; M < 3; ++M) o[M] += s_w[WO_011 + n * 3 + M] * p;
        }
        float* op = out1 + (size_t)c * 3;
#pragma unroll
        for (int M = 0; M < 3; ++M) op[M] = o[M];
    }

    // ---------------- pair (0,2): (0,2,2) -> out2 block 0 ----------------
    {
        float o[5] = {0.f, 0.f, 0.f, 0.f, 0.f};
#pragma unroll
        for (int n = 0; n < 5; ++n) {
            const float p = a0 * b2n[n];
#pragma unroll
            for (int M = 0; M < 5; ++M) o[M] += s_w[WO_022 + n * 5 + M] * p;
        }
        float* op = out2 + (size_t)c * 5;
#pragma unroll
        for (int M = 0; M < 5; ++M) op[M] = o[M];
    }

    // ---------------- pair (1,1): (1,1,0),(1,1,1),(1,1,2) ----------------
    {
        float p[9];
#pragma unroll
        for (int m = 0; m < 3; ++m)
#pragma unroll
            for (int n = 0; n < 3; ++n) p[m * 3 + n] = a1m[m] * b1n[n];

        // l3 = 0 -> out0 block 1
        {
            float o = 0.f;
#pragma unroll
            for (int k = 0; k < 9; ++k) o += s_w[WO_110 + k] * p[k];
            out0[4096 + c] = o;
        }
        // l3 = 1 -> out1 block 1
        {
            float o[3] = {0.f, 0.f, 0.f};
#pragma unroll
            for (int k = 0; k < 9; ++k)
#pragma unroll
                for (int M = 0; M < 3; ++M) o[M] += s_w[WO_111 + k * 3 + M] * p[k];
            float* op = out1 + (size_t)(4096 + c) * 3;
#pragma unroll
            for (int M = 0; M < 3; ++M) op[M] = o[M];
        }
        // l3 = 2 -> out2 block 1
        {
            float o[5] = {0.f, 0.f, 0.f, 0.f, 0.f};
#pragma unroll
            for (int k = 0; k < 9; ++k)
#pragma unroll
                for (int M = 0; M < 5; ++M) o[M] += s_w[WO_112 + k * 5 + M] * p[k];
            float* op = out2 + (size_t)(4096 + c) * 5;
#pragma unroll
            for (int M = 0; M < 5; ++M) op[M] = o[M];
        }
    }

    // ---------------- pair (1,2): (1,2,1),(1,2,2) ----------------
    {
        float p[15];
#pragma unroll
        for (int m = 0; m < 3; ++m)
#pragma unroll
            for (int n = 0; n < 5; ++n) p[m * 5 + n] = a1m[m] * b2n[n];

        // l3 = 1 -> out1 block 2
        {
            float o[3] = {0.f, 0.f, 0.f};
#pragma unroll
            for (int k = 0; k < 15; ++k)
#pragma unroll
                for (int M = 0; M < 3; ++M) o[M] += s_w[WO_121 + k * 3 + M] * p[k];
            float* op = out1 + (size_t)(2 * 4096 + c) * 3;
#pragma unroll
            for (int M = 0; M < 3; ++M) op[M] = o[M];
        }
        // l3 = 2 -> out2 block 2
        {
            float o[5] = {0.f, 0.f, 0.f, 0.f, 0.f};
#pragma unroll
            for (int k = 0; k < 15; ++k)
#pragma unroll
                for (int M = 0; M < 5; ++M) o[M] += s_w[WO_122 + k * 5 + M] * p[k];
            float* op = out2 + (size_t)(2 * 4096 + c) * 5;
#pragma unroll
            for (int M = 0; M < 5; ++M) op[M] = o[M];
        }
    }

    // ---------------- pair (2,2): (2,2,0),(2,2,1),(2,2,2) ----------------
    {
        float p[25];
#pragma unroll
        for (int m = 0; m < 5; ++m)
#pragma unroll
            for (int n = 0; n < 5; ++n) p[m * 5 + n] = a2m[m] * b2n[n];

        // l3 = 0 -> out0 block 2
        {
            float o = 0.f;
#pragma unroll
            for (int k = 0; k < 25; ++k) o += s_w[WO_220 + k] * p[k];
            out0[2 * 4096 + c] = o;
        }
        // l3 = 1 -> out1 block 3
        {
            float o[3] = {0.f, 0.f, 0.f};
#pragma unroll
            for (int k = 0; k < 25; ++k)
#pragma unroll
                for (int M = 0; M < 3; ++M) o[M] += s_w[WO_221 + k * 3 + M] * p[k];
            float* op = out1 + (size_t)(3 * 4096 + c) * 3;
#pragma unroll
            for (int M = 0; M < 3; ++M) op[M] = o[M];
        }
        // l3 = 2 -> out2 block 3
        {
            float o[5] = {0.f, 0.f, 0.f, 0.f, 0.f};
#pragma unroll
            for (int k = 0; k < 25; ++k)
#pragma unroll
                for (int M = 0; M < 5; ++M) o[M] += s_w[WO_222 + k * 5 + M] * p[k];
            float* op = out2 + (size_t)(3 * 4096 + c) * 5;
#pragma unroll
            for (int M = 0; M < 5; ++M) op[M] = o[M];
        }
    }
}

extern "C" void kernel_launch(void* const* d_in, const int* in_sizes, int n_in,
                              void* d_out, int out_size, void* d_ws, size_t ws_size,
                              hipStream_t stream) {
    const float* x0   = (const float*)d_in[0];
    const float* x1   = (const float*)d_in[1];
    const float* x2   = (const float*)d_in[2];
    const float* w000 = (const float*)d_in[3];
    const float* w011 = (const float*)d_in[4];
    const float* w022 = (const float*)d_in[5];
    const float* w110 = (const float*)d_in[6];
    const float* w111 = (const float*)d_in[7];
    const float* w112 = (const float*)d_in[8];
    const float* w121 = (const float*)d_in[9];
    const float* w122 = (const float*)d_in[10];
    const float* w220 = (const float*)d_in[11];
    const float* w221 = (const float*)d_in[12];
    const float* w222 = (const float*)d_in[13];
    float* outp = (float*)d_out;

    dim3 grid(512 * 16);
    dim3 block(256);
    tp_kernel<<<grid, block, 0, stream>>>(x0, x1, x2,
                                          w000, w011, w022, w110, w111, w112,
                                          w121, w122, w220, w221, w222, outp);
}

// Round 2
// 318.363 us; speedup vs baseline: 1.0820x; 1.0820x over previous
//
#include <hip/hip_runtime.h>

// Tensor-product nonlinearity, B=512, MUL=64, l in {0,1,2}.
// out0: (512, 3*4096, 1), out1: (512, 4*4096, 3), out2: (512, 4*4096, 5)
// flat-concatenated in d_out in that order.
//
// Round-2 design:
//  - weights read straight from global with wave-uniform addresses -> s_load
//    (SGPR operands for v_fma), zero LDS traffic for weights.
//  - out0 stored directly (stride-1, coalesced).
//  - out1/out2 staged in LDS (stride-3/5 staging writes = 2-way bank alias,
//    free), then written back as float4 fully-coalesced chunks.

#define OUT1_BASE (512 * 12288)               // 6291456
#define OUT2_BASE (OUT1_BASE + 512 * 49152)   // 31457280

__global__ __launch_bounds__(256) void tp_kernel(
    const float* __restrict__ x0, const float* __restrict__ x1, const float* __restrict__ x2,
    const float* __restrict__ w000, const float* __restrict__ w011, const float* __restrict__ w022,
    const float* __restrict__ w110, const float* __restrict__ w111, const float* __restrict__ w112,
    const float* __restrict__ w121, const float* __restrict__ w122,
    const float* __restrict__ w220, const float* __restrict__ w221, const float* __restrict__ w222,
    float* __restrict__ out)
{
    // out1 staging: 4 chunks x 768 floats at [0, 3072)
    // out2 staging: 4 chunks x 1280 floats at [3072, 8192)
    __shared__ __align__(16) float s_out[8192];   // 32 KiB

    const int b    = blockIdx.x >> 4;   // 0..511
    const int tile = blockIdx.x & 15;   // 0..15
    const int t    = threadIdx.x;       // 0..255
    const int c    = tile * 256 + t;    // 0..4095 = i*64 + j
    const int i    = c >> 6;            // wave-uniform
    const int j    = c & 63;            // = lane id

    // ---- x fragments: a-side wave-uniform, b-side lane-contiguous ----
    const float a0 = x0[b * 64 + i];
    const float b0 = x0[b * 64 + j];
    float a1[3], b1[3], a2[5], b2[5];
#pragma unroll
    for (int m = 0; m < 3; ++m) a1[m] = x1[b * 192 + i * 3 + m];
#pragma unroll
    for (int n = 0; n < 3; ++n) b1[n] = x1[b * 192 + j * 3 + n];
#pragma unroll
    for (int m = 0; m < 5; ++m) a2[m] = x2[b * 320 + i * 5 + m];
#pragma unroll
    for (int n = 0; n < 5; ++n) b2[n] = x2[b * 320 + j * 5 + n];

    float* __restrict__ out0 = out + (size_t)b * 12288;

    // ---------------- pair (0,0): (0,0,0) -> out0 chunk 0 (direct) --------
    out0[c] = w000[0] * (a0 * b0);

    // ---------------- pair (0,1): (0,1,1) -> out1 chunk 0 -----------------
    {
        float o[3] = {0.f, 0.f, 0.f};
#pragma unroll
        for (int n = 0; n < 3; ++n) {
            const float p = a0 * b1[n];
#pragma unroll
            for (int M = 0; M < 3; ++M) o[M] += w011[n * 3 + M] * p;
        }
#pragma unroll
        for (int M = 0; M < 3; ++M) s_out[0 * 768 + t * 3 + M] = o[M];
    }

    // ---------------- pair (0,2): (0,2,2) -> out2 chunk 0 -----------------
    {
        float o[5] = {0.f, 0.f, 0.f, 0.f, 0.f};
#pragma unroll
        for (int n = 0; n < 5; ++n) {
            const float p = a0 * b2[n];
#pragma unroll
            for (int M = 0; M < 5; ++M) o[M] += w022[n * 5 + M] * p;
        }
#pragma unroll
        for (int M = 0; M < 5; ++M) s_out[3072 + 0 * 1280 + t * 5 + M] = o[M];
    }

    // ---------------- pair (1,1): (1,1,0),(1,1,1),(1,1,2) -----------------
    {
        float p[9];
#pragma unroll
        for (int m = 0; m < 3; ++m)
#pragma unroll
            for (int n = 0; n < 3; ++n) p[m * 3 + n] = a1[m] * b1[n];

        {   // l3=0 -> out0 chunk 1 (direct)
            float o = 0.f;
#pragma unroll
            for (int k = 0; k < 9; ++k) o += w110[k] * p[k];
            out0[4096 + c] = o;
        }
        {   // l3=1 -> out1 chunk 1
            float o[3] = {0.f, 0.f, 0.f};
#pragma unroll
            for (int k = 0; k < 9; ++k)
#pragma unroll
                for (int M = 0; M < 3; ++M) o[M] += w111[k * 3 + M] * p[k];
#pragma unroll
            for (int M = 0; M < 3; ++M) s_out[1 * 768 + t * 3 + M] = o[M];
        }
        {   // l3=2 -> out2 chunk 1
            float o[5] = {0.f, 0.f, 0.f, 0.f, 0.f};
#pragma unroll
            for (int k = 0; k < 9; ++k)
#pragma unroll
                for (int M = 0; M < 5; ++M) o[M] += w112[k * 5 + M] * p[k];
#pragma unroll
            for (int M = 0; M < 5; ++M) s_out[3072 + 1 * 1280 + t * 5 + M] = o[M];
        }
    }

    // ---------------- pair (1,2): (1,2,1),(1,2,2) -------------------------
    {
        float p[15];
#pragma unroll
        for (int m = 0; m < 3; ++m)
#pragma unroll
            for (int n = 0; n < 5; ++n) p[m * 5 + n] = a1[m] * b2[n];

        {   // l3=1 -> out1 chunk 2
            float o[3] = {0.f, 0.f, 0.f};
#pragma unroll
            for (int k = 0; k < 15; ++k)
#pragma unroll
                for (int M = 0; M < 3; ++M) o[M] += w121[k * 3 + M] * p[k];
#pragma unroll
            for (int M = 0; M < 3; ++M) s_out[2 * 768 + t * 3 + M] = o[M];
        }
        {   // l3=2 -> out2 chunk 2
            float o[5] = {0.f, 0.f, 0.f, 0.f, 0.f};
#pragma unroll
            for (int k = 0; k < 15; ++k)
#pragma unroll
                for (int M = 0; M < 5; ++M) o[M] += w122[k * 5 + M] * p[k];
#pragma unroll
            for (int M = 0; M < 5; ++M) s_out[3072 + 2 * 1280 + t * 5 + M] = o[M];
        }
    }

    // ---------------- pair (2,2): (2,2,0),(2,2,1),(2,2,2) -----------------
    {
        float p[25];
#pragma unroll
        for (int m = 0; m < 5; ++m)
#pragma unroll
            for (int n = 0; n < 5; ++n) p[m * 5 + n] = a2[m] * b2[n];

        {   // l3=0 -> out0 chunk 2 (direct)
            float o = 0.f;
#pragma unroll
            for (int k = 0; k < 25; ++k) o += w220[k] * p[k];
            out0[2 * 4096 + c] = o;
        }
        {   // l3=1 -> out1 chunk 3
            float o[3] = {0.f, 0.f, 0.f};
#pragma unroll
            for (int k = 0; k < 25; ++k)
#pragma unroll
                for (int M = 0; M < 3; ++M) o[M] += w221[k * 3 + M] * p[k];
#pragma unroll
            for (int M = 0; M < 3; ++M) s_out[3 * 768 + t * 3 + M] = o[M];
        }
        {   // l3=2 -> out2 chunk 3
            float o[5] = {0.f, 0.f, 0.f, 0.f, 0.f};
#pragma unroll
            for (int k = 0; k < 25; ++k)
#pragma unroll
                for (int M = 0; M < 5; ++M) o[M] += w222[k * 5 + M] * p[k];
#pragma unroll
            for (int M = 0; M < 5; ++M) s_out[3072 + 3 * 1280 + t * 5 + M] = o[M];
        }
    }

    __syncthreads();

    // ---- coalesced float4 writeback: 2048 float4 / block = 8 x 256 ------
    // all chunk boundaries (in f4 units) are multiples of 64 -> no intra-wave
    // divergence in the branch below.
    const float4* __restrict__ s4 = (const float4*)s_out;
#pragma unroll
    for (int k = 0; k < 8; ++k) {
        const int fi = k * 256 + t;          // 0..2047
        const float4 v = s4[fi];
        int dst;
        if (fi < 768) {                      // out1 region: 4 chunks x 192 f4
            const int q   = fi / 192;
            const int off = fi % 192;
            dst = OUT1_BASE + b * 49152 + q * 12288 + tile * 768 + 4 * off;
        } else {                             // out2 region: 4 chunks x 320 f4
            const int r   = fi - 768;
            const int q   = r / 320;
            const int off = r % 320;
            dst = OUT2_BASE + b * 81920 + q * 20480 + tile * 1280 + 4 * off;
        }
        *(float4*)(out + dst) = v;
    }
}

extern "C" void kernel_launch(void* const* d_in, const int* in_sizes, int n_in,
                              void* d_out, int out_size, void* d_ws, size_t ws_size,
                              hipStream_t stream) {
    const float* x0   = (const float*)d_in[0];
    const float* x1   = (const float*)d_in[1];
    const float* x2   = (const float*)d_in[2];
    const float* w000 = (const float*)d_in[3];
    const float* w011 = (const float*)d_in[4];
    const float* w022 = (const float*)d_in[5];
    const float* w110 = (const float*)d_in[6];
    const float* w111 = (const float*)d_in[7];
    const float* w112 = (const float*)d_in[8];
    const float* w121 = (const float*)d_in[9];
    const float* w122 = (const float*)d_in[10];
    const float* w220 = (const float*)d_in[11];
    const float* w221 = (const float*)d_in[12];
    const float* w222 = (const float*)d_in[13];
    float* outp = (float*)d_out;

    dim3 grid(512 * 16);
    dim3 block(256);
    tp_kernel<<<grid, block, 0, stream>>>(x0, x1, x2,
                                          w000, w011, w022, w110, w111, w112,
                                          w121, w122, w220, w221, w222, outp);
}